// Round 6
// baseline (78.461 us; speedup 1.0000x reference)
//
#include <hip/hip_runtime.h>

// SRHT via MFMA, row-batched + rotated pipeline.
// Per row: 6 mfma_f32_32x32x16_f16 products (verified R2-R5 structure):
//   P1(B),P2(B)=fwht1; P3(Bs),P4(B)=fwht2*(1/32); P5(Bs),P6(B)=fwht3*(1/32).
// Invariants in registers: B/Bs fragments, rad0/1/2 packed f16 sign masks
// (xor after cvt_pkrtz == exact +-1 mult), perm indices. x loads wave-coalesced
// (lane q reads x[32k+q]), prefetched one row ahead.
// R6: region between barriers is  gather(i)+out-store(i)  THEN  chain(i+1)+
// store_h(i+1)  (opposite LDS buffers -> legal). Out stores issue right after
// each barrier = continuous HBM write drain; MFMA chain overlaps LDS traffic.

typedef float f32x16 __attribute__((ext_vector_type(16)));
typedef __fp16 f16x8 __attribute__((ext_vector_type(8)));
typedef unsigned int uintv2 __attribute__((ext_vector_type(2)));

union H8U4 { f16x8 h; unsigned int u[4]; };

#define RPB 8  // rows per block

__device__ __forceinline__ unsigned int pkrtz(float a, float b) {
  auto p = __builtin_amdgcn_cvt_pkrtz(a, b);   // lo = f16(a), hi = f16(b)
  return __builtin_bit_cast(unsigned int, p);
}

__device__ __forceinline__ f32x16 prod(const f16x8& A0, const f16x8& A1,
                                       const f16x8& B0, const f16x8& B1) {
  f32x16 z = {0.f,0.f,0.f,0.f, 0.f,0.f,0.f,0.f, 0.f,0.f,0.f,0.f, 0.f,0.f,0.f,0.f};
  z = __builtin_amdgcn_mfma_f32_32x32x16_f16(A0, B0, z, 0, 0, 0);
  z = __builtin_amdgcn_mfma_f32_32x32x16_f16(A1, B1, z, 0, 0, 0);
  return z;
}

// C (col=lane&31, row=(j&3)+8*(j>>2)+4*hi) -> A fragments of C^T,
// with optional packed sign-mask XOR (rad multiply) pre-swap.
template <bool RADM>
__device__ __forceinline__ void convA(const f32x16& c, const unsigned (&msk)[8],
                                      f16x8& A0, f16x8& A1) {
  unsigned W[8];
#pragma unroll
  for (int m = 0; m < 8; m++) {
    unsigned wd = pkrtz(c[2 * m], c[2 * m + 1]);
    if (RADM) wd ^= msk[m];
    W[m] = wd;
  }
  H8U4 a0, a1; uintv2 r;
  r = __builtin_amdgcn_permlane32_swap(W[0], W[2], false, false); a0.u[0]=r[0]; a0.u[2]=r[1];
  r = __builtin_amdgcn_permlane32_swap(W[1], W[3], false, false); a0.u[1]=r[0]; a0.u[3]=r[1];
  r = __builtin_amdgcn_permlane32_swap(W[4], W[6], false, false); a1.u[0]=r[0]; a1.u[2]=r[1];
  r = __builtin_amdgcn_permlane32_swap(W[5], W[7], false, false); a1.u[1]=r[0]; a1.u[3]=r[1];
  A0 = a0.h; A1 = a1.h;
}

__device__ __forceinline__ void packA(const float (&xr)[16], const unsigned (&r0m)[8],
                                      f16x8& A0, f16x8& A1) {
  H8U4 a0, a1;
#pragma unroll
  for (int m = 0; m < 4; m++) {
    a0.u[m] = pkrtz(xr[2*m],     xr[2*m + 1]) ^ r0m[m];
    a1.u[m] = pkrtz(xr[8 + 2*m], xr[8 + 2*m + 1]) ^ r0m[4 + m];
  }
  A0 = a0.h; A1 = a1.h;
}

__device__ __forceinline__ void loadX(const float* __restrict__ xp, float (&xr)[16],
                                      int hi) {
#pragma unroll
  for (int t = 0; t < 2; t++)
#pragma unroll
    for (int m = 0; m < 4; m++) {
      int k0 = 16*t + 8*hi + 2*m;
      xr[(4*t+m)*2 + 0] = xp[k0 << 5];
      xr[(4*t+m)*2 + 1] = xp[(k0 + 1) << 5];
    }
}

__device__ __forceinline__ f32x16 chain6(f16x8 A0, f16x8 A1,
                                         const f16x8& B0, const f16x8& B1,
                                         const f16x8& Bs0, const f16x8& Bs1,
                                         const unsigned (&r0m)[8],
                                         const unsigned (&r1m)[8],
                                         const unsigned (&r2m)[8]) {
  f32x16 c;
  c = prod(A0, A1, B0, B1);            // P1
  convA<false>(c, r0m, A0, A1);
  c = prod(A0, A1, B0, B1);            // P2 = fwht1
  convA<true>(c, r1m, A0, A1);
  c = prod(A0, A1, Bs0, Bs1);          // P3 (carries 1/32)
  convA<false>(c, r0m, A0, A1);
  c = prod(A0, A1, B0, B1);            // P4 = fwht2/32
  convA<true>(c, r2m, A0, A1);
  c = prod(A0, A1, Bs0, Bs1);          // P5 (carries 1/32)
  convA<false>(c, r0m, A0, A1);
  c = prod(A0, A1, B0, B1);            // P6 = h : c[j] = h[32*p(j)+q]
  return c;
}

__global__ __launch_bounds__(256) void srht_kernel(
    const float* __restrict__ x, const float* __restrict__ rad,
    const int* __restrict__ perm, float* __restrict__ out) {
  __shared__ __align__(16) float lds[8192];   // 2 x 4096 (double-buffered h)
  const int tid  = threadIdx.x;
  const int w    = tid >> 6;        // FWHT block
  const int lane = tid & 63;
  const int q    = lane & 31;
  const int hi   = lane >> 5;
  const size_t row0 = (size_t)blockIdx.x * RPB;

  // ---- B / Bs fragments via XOR chain (sign(H[k][q]) = popc(k&q)&1) ----
  f16x8 B0, B1, Bs0, Bs1;
  {
    unsigned sb  = (hi & (q >> 3)) & 1u;
    unsigned sx  = (sb * 0x80008000u) ^ ((unsigned)(q & 1) << 31);
    unsigned m2  = (q & 2)  ? 0x80008000u : 0u;
    unsigned m4  = (q & 4)  ? 0x80008000u : 0u;
    unsigned m16 = (q & 16) ? 0x80008000u : 0u;
    H8U4 b0, b1, s0, s1;
    unsigned u0 = 0x3C003C00u ^ sx;   // +-1.0
    unsigned v0 = 0x28002800u ^ sx;   // +-2^-5
    b0.u[0]=u0; b0.u[1]=u0^m2; b0.u[2]=u0^m4; b0.u[3]=u0^m2^m4;
    s0.u[0]=v0; s0.u[1]=v0^m2; s0.u[2]=v0^m4; s0.u[3]=v0^m2^m4;
#pragma unroll
    for (int m = 0; m < 4; m++) { b1.u[m]=b0.u[m]^m16; s1.u[m]=s0.u[m]^m16; }
    B0=b0.h; B1=b1.h; Bs0=s0.h; Bs1=s1.h;
  }

  // ---- rad sign masks (loaded once; wave-coalesced scalar reads) ----
  unsigned r0m[8], r1m[8], r2m[8];
  {
    const float* r0 = rad + (w << 10) + q;
    const float* r1 = rad + ((4 + w) << 10) + q;
    const float* r2 = rad + ((8 + w) << 10) + q;
#pragma unroll
    for (int t = 0; t < 2; t++)
#pragma unroll
      for (int m = 0; m < 4; m++) {
        int k0 = 16*t + 8*hi + 2*m;   // A-word (t,m) packs rows k0, k0+1
        unsigned sa = __float_as_uint(r0[k0 << 5]) >> 31;
        unsigned sc = __float_as_uint(r0[(k0 + 1) << 5]) >> 31;
        r0m[4*t + m] = (sa << 15) | (sc << 31);
      }
#pragma unroll
    for (int m = 0; m < 8; m++) {     // convA word m packs c[2m], c[2m+1]
      int j0 = 2*m, j1 = 2*m + 1;
      int p0 = (j0 & 3) + ((j0 >> 2) << 3) + (hi << 2);
      int p1 = (j1 & 3) + ((j1 >> 2) << 3) + (hi << 2);
      r1m[m] = ((__float_as_uint(r1[p0 << 5]) >> 31) << 15) |
               ((__float_as_uint(r1[p1 << 5]) >> 31) << 31);
      r2m[m] = ((__float_as_uint(r2[p0 << 5]) >> 31) << 15) |
               ((__float_as_uint(r2[p1 << 5]) >> 31) << 31);
    }
  }

  // ---- perm indices, loaded once (coalesced int4) ----
  int pidx[16];
#pragma unroll
  for (int g = 0; g < 4; g++) {
    int4 pi = *(const int4*)(perm + (g << 10) + (tid << 2));
    pidx[4*g+0]=pi.x; pidx[4*g+1]=pi.y; pidx[4*g+2]=pi.z; pidx[4*g+3]=pi.w;
  }

  const float* xb = x + row0 * 1024 + q;
  const int hbase = (w << 10);

  // ---- prologue: row 0 chain + h-store (buf 0) ----
  float xr[16];
  loadX(xb, xr, hi);
  {
    f16x8 A0, A1;
    packA(xr, r0m, A0, A1);
    loadX(xb + 1024, xr, hi);              // prefetch row 1
    f32x16 c = chain6(A0, A1, B0, B1, Bs0, Bs1, r0m, r1m, r2m);
#pragma unroll
    for (int j = 0; j < 16; j++) {
      int p = (j & 3) + ((j >> 2) << 3) + (hi << 2);
      lds[hbase + (p << 5) + q] = c[j];
    }
  }

  for (int i = 0; i < RPB; i++) {
    __syncthreads();
    // gather row i from buf[i&1]; out stores issue immediately (HBM drain)
    const float* buf = lds + ((i & 1) << 12);
    float* orow = out + (row0 + i) * 4096;
#pragma unroll
    for (int g = 0; g < 4; g++) {
      float4 o;
      o.x = buf[pidx[4*g+0]];
      o.y = buf[pidx[4*g+1]];
      o.z = buf[pidx[4*g+2]];
      o.w = buf[pidx[4*g+3]];
      *(float4*)(orow + (g << 10) + (tid << 2)) = o;
    }
    // chain row i+1 into the opposite buffer (overlaps with gather above)
    if (i + 1 < RPB) {
      f16x8 A0, A1;
      packA(xr, r0m, A0, A1);
      if (i + 2 < RPB) loadX(xb + (size_t)(i + 2) * 1024, xr, hi);
      f32x16 c = chain6(A0, A1, B0, B1, Bs0, Bs1, r0m, r1m, r2m);
      float* nbuf = lds + (((i + 1) & 1) << 12);
#pragma unroll
      for (int j = 0; j < 16; j++) {
        int p = (j & 3) + ((j >> 2) << 3) + (hi << 2);
        nbuf[hbase + (p << 5) + q] = c[j];
      }
    }
  }
}

extern "C" void kernel_launch(void* const* d_in, const int* in_sizes, int n_in,
                              void* d_out, int out_size, void* d_ws, size_t ws_size,
                              hipStream_t stream) {
  (void)n_in; (void)d_ws; (void)ws_size; (void)out_size;
  const float* x    = (const float*)d_in[0];
  const float* rad  = (const float*)d_in[1];
  const int*   perm = (const int*)d_in[2];
  float*       out  = (float*)d_out;
  const int rows = in_sizes[0] / 1024;  // 16384
  srht_kernel<<<rows / RPB, 256, 0, stream>>>(x, rad, perm, out);
}

// Round 8
// 56.845 us; speedup vs baseline: 1.3803x; 1.3803x over previous
//
#include <hip/hip_runtime.h>

// SRHT via MFMA, row-batched (R5 structure; R6 rotation was neutral).
// Per row: 6 mfma_f32_32x32x16_f16 products:
//   P1,P2 = fwht1; P3,P4 = fwht2*(1/32); P5,P6 = fwht3*(1/32)
// 1/32 folded into convA<true>'s f32 multiply (exact exponent shift in f16;
// replaces Bs fragments -> -8 VGPR). perm reloaded per row (L2-resident,
// coalesced) instead of register-pinned pidx -> -16 VGPR.
// __launch_bounds__(256,5): 5 waves/SIMD for store-drain smoothing.
// Out stores nontemporal via clang ext_vector f32x4 (HIP float4 rejected by
// __builtin_nontemporal_store).

typedef float f32x16 __attribute__((ext_vector_type(16)));
typedef float f32x4  __attribute__((ext_vector_type(4)));
typedef __fp16 f16x8 __attribute__((ext_vector_type(8)));
typedef unsigned int uintv2 __attribute__((ext_vector_type(2)));

union H8U4 { f16x8 h; unsigned int u[4]; };

#define RPB 8  // rows per block

__device__ __forceinline__ unsigned int pkrtz(float a, float b) {
  auto p = __builtin_amdgcn_cvt_pkrtz(a, b);   // lo = f16(a), hi = f16(b)
  return __builtin_bit_cast(unsigned int, p);
}

__device__ __forceinline__ f32x16 prod(const f16x8& A0, const f16x8& A1,
                                       const f16x8& B0, const f16x8& B1) {
  f32x16 z = {0.f,0.f,0.f,0.f, 0.f,0.f,0.f,0.f, 0.f,0.f,0.f,0.f, 0.f,0.f,0.f,0.f};
  z = __builtin_amdgcn_mfma_f32_32x32x16_f16(A0, B0, z, 0, 0, 0);
  z = __builtin_amdgcn_mfma_f32_32x32x16_f16(A1, B1, z, 0, 0, 0);
  return z;
}

// C (col=lane&31, row=(j&3)+8*(j>>2)+4*hi) -> A fragments of C^T.
// RADM: multiply by 1/32 (exact in f16) and XOR the rad sign mask pre-swap.
template <bool RADM>
__device__ __forceinline__ void convA(const f32x16& c, const unsigned (&msk)[8],
                                      f16x8& A0, f16x8& A1) {
  unsigned W[8];
#pragma unroll
  for (int m = 0; m < 8; m++) {
    unsigned wd;
    if (RADM) wd = pkrtz(c[2*m] * 0.03125f, c[2*m + 1] * 0.03125f) ^ msk[m];
    else      wd = pkrtz(c[2*m], c[2*m + 1]);
    W[m] = wd;
  }
  H8U4 a0, a1; uintv2 r;
  r = __builtin_amdgcn_permlane32_swap(W[0], W[2], false, false); a0.u[0]=r[0]; a0.u[2]=r[1];
  r = __builtin_amdgcn_permlane32_swap(W[1], W[3], false, false); a0.u[1]=r[0]; a0.u[3]=r[1];
  r = __builtin_amdgcn_permlane32_swap(W[4], W[6], false, false); a1.u[0]=r[0]; a1.u[2]=r[1];
  r = __builtin_amdgcn_permlane32_swap(W[5], W[7], false, false); a1.u[1]=r[0]; a1.u[3]=r[1];
  A0 = a0.h; A1 = a1.h;
}

__device__ __forceinline__ void packA(const float (&xr)[16], const unsigned (&r0m)[8],
                                      f16x8& A0, f16x8& A1) {
  H8U4 a0, a1;
#pragma unroll
  for (int m = 0; m < 4; m++) {
    a0.u[m] = pkrtz(xr[2*m],     xr[2*m + 1]) ^ r0m[m];
    a1.u[m] = pkrtz(xr[8 + 2*m], xr[8 + 2*m + 1]) ^ r0m[4 + m];
  }
  A0 = a0.h; A1 = a1.h;
}

__device__ __forceinline__ void loadX(const float* __restrict__ xp, float (&xr)[16],
                                      int hi) {
#pragma unroll
  for (int t = 0; t < 2; t++)
#pragma unroll
    for (int m = 0; m < 4; m++) {
      int k0 = 16*t + 8*hi + 2*m;
      xr[(4*t+m)*2 + 0] = xp[k0 << 5];
      xr[(4*t+m)*2 + 1] = xp[(k0 + 1) << 5];
    }
}

__device__ __forceinline__ f32x16 chain6(f16x8 A0, f16x8 A1,
                                         const f16x8& B0, const f16x8& B1,
                                         const unsigned (&r0m)[8],
                                         const unsigned (&r1m)[8],
                                         const unsigned (&r2m)[8]) {
  f32x16 c;
  c = prod(A0, A1, B0, B1);            // P1
  convA<false>(c, r0m, A0, A1);
  c = prod(A0, A1, B0, B1);            // P2 = fwht1
  convA<true>(c, r1m, A0, A1);         // *rad1/32
  c = prod(A0, A1, B0, B1);            // P3
  convA<false>(c, r0m, A0, A1);
  c = prod(A0, A1, B0, B1);            // P4 = fwht2/32
  convA<true>(c, r2m, A0, A1);         // *rad2/32
  c = prod(A0, A1, B0, B1);            // P5
  convA<false>(c, r0m, A0, A1);
  c = prod(A0, A1, B0, B1);            // P6 = h : c[j] = h[32*p(j)+q]
  return c;
}

__global__ __launch_bounds__(256, 5) void srht_kernel(
    const float* __restrict__ x, const float* __restrict__ rad,
    const int* __restrict__ perm, float* __restrict__ out) {
  __shared__ __align__(16) float lds[8192];   // 2 x 4096 (double-buffered h)
  const int tid  = threadIdx.x;
  const int w    = tid >> 6;        // FWHT block
  const int lane = tid & 63;
  const int q    = lane & 31;
  const int hi   = lane >> 5;
  const size_t row0 = (size_t)blockIdx.x * RPB;

  // ---- B fragments via XOR chain (sign(H[k][q]) = popc(k&q)&1) ----
  f16x8 B0, B1;
  {
    unsigned sb  = (hi & (q >> 3)) & 1u;
    unsigned sx  = (sb * 0x80008000u) ^ ((unsigned)(q & 1) << 31);
    unsigned m2  = (q & 2)  ? 0x80008000u : 0u;
    unsigned m4  = (q & 4)  ? 0x80008000u : 0u;
    unsigned m16 = (q & 16) ? 0x80008000u : 0u;
    H8U4 b0, b1;
    unsigned u0 = 0x3C003C00u ^ sx;   // +-1.0
    b0.u[0]=u0; b0.u[1]=u0^m2; b0.u[2]=u0^m4; b0.u[3]=u0^m2^m4;
#pragma unroll
    for (int m = 0; m < 4; m++) b1.u[m] = b0.u[m] ^ m16;
    B0=b0.h; B1=b1.h;
  }

  // ---- rad sign masks (loaded once; wave-coalesced scalar reads) ----
  unsigned r0m[8], r1m[8], r2m[8];
  {
    const float* r0 = rad + (w << 10) + q;
    const float* r1 = rad + ((4 + w) << 10) + q;
    const float* r2 = rad + ((8 + w) << 10) + q;
#pragma unroll
    for (int t = 0; t < 2; t++)
#pragma unroll
      for (int m = 0; m < 4; m++) {
        int k0 = 16*t + 8*hi + 2*m;   // A-word (t,m) packs rows k0, k0+1
        unsigned sa = __float_as_uint(r0[k0 << 5]) >> 31;
        unsigned sc = __float_as_uint(r0[(k0 + 1) << 5]) >> 31;
        r0m[4*t + m] = (sa << 15) | (sc << 31);
      }
#pragma unroll
    for (int m = 0; m < 8; m++) {     // convA word m packs c[2m], c[2m+1]
      int j0 = 2*m, j1 = 2*m + 1;
      int p0 = (j0 & 3) + ((j0 >> 2) << 3) + (hi << 2);
      int p1 = (j1 & 3) + ((j1 >> 2) << 3) + (hi << 2);
      r1m[m] = ((__float_as_uint(r1[p0 << 5]) >> 31) << 15) |
               ((__float_as_uint(r1[p1 << 5]) >> 31) << 31);
      r2m[m] = ((__float_as_uint(r2[p0 << 5]) >> 31) << 15) |
               ((__float_as_uint(r2[p1 << 5]) >> 31) << 31);
    }
  }

  const float* xb = x + row0 * 1024 + q;
  const int hbase = (w << 10);

  // ---- x prologue: row 0 ----
  float xr[16];
  loadX(xb, xr, hi);

  for (int i = 0; i < RPB; i++) {
    f16x8 A0, A1;
    packA(xr, r0m, A0, A1);
    if (i + 1 < RPB) loadX(xb + (size_t)(i + 1) * 1024, xr, hi);  // prefetch

    f32x16 c = chain6(A0, A1, B0, B1, r0m, r1m, r2m);

    // h -> LDS buf[i&1] at true index (bank = q, 2-way = free)
    float* buf = lds + ((i & 1) << 12);
#pragma unroll
    for (int j = 0; j < 16; j++) {
      int p = (j & 3) + ((j >> 2) << 3) + (hi << 2);
      buf[hbase + (p << 5) + q] = c[j];
    }
    __syncthreads();   // double-buffer: one barrier per row

    // gather: perm reloaded per row (L2-resident), nontemporal f32x4 stores
    float* orow = out + (row0 + i) * 4096;
#pragma unroll
    for (int g = 0; g < 4; g++) {
      int4 pi = *(const int4*)(perm + (g << 10) + (tid << 2));
      f32x4 o;
      o.x = buf[pi.x];
      o.y = buf[pi.y];
      o.z = buf[pi.z];
      o.w = buf[pi.w];
      __builtin_nontemporal_store(o, (f32x4*)(orow + (g << 10) + (tid << 2)));
    }
  }
}

extern "C" void kernel_launch(void* const* d_in, const int* in_sizes, int n_in,
                              void* d_out, int out_size, void* d_ws, size_t ws_size,
                              hipStream_t stream) {
  (void)n_in; (void)d_ws; (void)ws_size; (void)out_size;
  const float* x    = (const float*)d_in[0];
  const float* rad  = (const float*)d_in[1];
  const int*   perm = (const int*)d_in[2];
  float*       out  = (float*)d_out;
  const int rows = in_sizes[0] / 1024;  // 16384
  srht_kernel<<<rows / RPB, 256, 0, stream>>>(x, rad, perm, out);
}